// Round 9
// baseline (232.793 us; speedup 1.0000x reference)
//
#include <hip/hip_runtime.h>

typedef unsigned short u16;
typedef __attribute__((ext_vector_type(8))) short bf16x8;   // 8 bf16 = 4 VGPRs
typedef __attribute__((ext_vector_type(4))) float f32x4;

#define B_   2
#define S_   2048
#define HID_ 1024
#define NH_  16
#define HD_  64
#define SCALE_ 0.125f            // 1/sqrt(64)
#define C2_   0.18033688011112f  // SCALE * log2(e)
#define CLAMP2_ 115.4156035f     // 80 * log2(e)
#define LOG2E_ 1.4426950408890f

__device__ __forceinline__ u16 f2bf(float f) {
    union { float f; unsigned int i; } v; v.f = f;
    unsigned int r = v.i + 0x7fffu + ((v.i >> 16) & 1u);   // RNE
    return (u16)(r >> 16);
}
__device__ __forceinline__ bf16x8 ld8(const u16* p) {
    return *reinterpret_cast<const bf16x8*>(p);
}
// packed fp32x2 -> bf16x2 (RNE), src0 in low half
__device__ __forceinline__ unsigned cvtpk(float lo, float hi) {
    unsigned r;
    asm("v_cvt_pk_bf16_f32 %0, %1, %2" : "=v"(r) : "v"(lo), "v"(hi));
    return r;
}
// native 2^x — single v_exp_f32 (exp2f is the slow libm-precise path)
__device__ __forceinline__ float ex2(float x) {
    float r;
    asm("v_exp_f32 %0, %1" : "=v"(r) : "v"(x));
    return r;
}
// async global->LDS, 16B per lane; l must be wave-uniform (HW adds lane*16)
__device__ __forceinline__ void gll16(const u16* g, const u16* l) {
    __builtin_amdgcn_global_load_lds(
        (const __attribute__((address_space(1))) unsigned int*)g,
        (__attribute__((address_space(3))) unsigned int*)l, 16, 0, 0);
}

// ---------------------------------------------------------------------------
// Stage 0: fused fp32->bf16 convert (blocks [0,3584)) + mask scan (blocks
// [3584,7680)).
// ---------------------------------------------------------------------------
__global__ __launch_bounds__(256) void conv_scan(
    const float* __restrict__ X, const float* __restrict__ W0,
    const float* __restrict__ W1, const float* __restrict__ W2,
    const unsigned* __restrict__ m,
    u16* __restrict__ Xb, u16* __restrict__ Wb, unsigned* __restrict__ flag)
{
    const int bx = blockIdx.x;
    if (bx < 3584) {
        const size_t s = (size_t)bx * 256 + threadIdx.x;
        const float* src; u16* dst; size_t off;
        if (s < 524288) { src = X; dst = Xb; off = s * 8; }
        else {
            const size_t t = s - 524288;
            const int w = (int)(t >> 17);
            off = (t & 131071) * 8;
            src = w == 0 ? W0 : w == 1 ? W1 : W2;
            dst = Wb + (size_t)w * 1048576;
        }
        f32x4 a = *(const f32x4*)(src + off);
        f32x4 b = *(const f32x4*)(src + off + 4);
        bf16x8 r;
        #pragma unroll
        for (int e = 0; e < 4; e++) { r[e] = (short)f2bf(a[e]); r[4 + e] = (short)f2bf(b[e]); }
        *(bf16x8*)(dst + off) = r;
    } else {
        const size_t i = ((size_t)(bx - 3584) * 256 + threadIdx.x) * 8;
        const uint4* p = (const uint4*)(m + i);
        uint4 a = p[0], b = p[1];
        const unsigned M = 0x7fffffffu;
        unsigned v = (a.x & M) | (a.y & M) | (a.z & M) | (a.w & M)
                   | (b.x & M) | (b.y & M) | (b.z & M) | (b.w & M);
        if (v) atomicOr(flag, 1u);
    }
}

// ---------------------------------------------------------------------------
// Stage 1: Y = Xb @ Wb^T + bias — R5-verified structure (BK=32, single-
// buffered gll16). Q is written PRE-SCALED by C2 = (1/8)*log2(e) so the
// attention QK^T lands directly in the log2 domain (kills 16 muls/tile/lane
// in attn). Epilogue bounces C through LDS for 16B stores; V transposed.
// ---------------------------------------------------------------------------
#define BK_ 32

__global__ __launch_bounds__(256) void qkv_mfma(
    const u16* __restrict__ Xb, const u16* __restrict__ Wb,
    const float* __restrict__ bq, const float* __restrict__ bk,
    const float* __restrict__ bv,
    u16* __restrict__ Q, u16* __restrict__ K, u16* __restrict__ V)
{
    __shared__ __align__(16) u16 As[128 * BK_];   // 8 KB, linear row-major
    __shared__ __align__(16) u16 Bs[128 * BK_];   // 8 KB

    const int tid  = threadIdx.x;
    const int wave = tid >> 6;
    const int lane = tid & 63;
    const int l16  = lane & 15;
    const int quad = lane >> 4;
    const int wr   = wave >> 1, wc = wave & 1;

    const int i0 = blockIdx.x * 128;
    const int j0 = blockIdx.y * 128;

    const int grow = (wave * 64 + lane) >> 2;       // 0..63
    const int gcol = (lane & 3) * 8;
    const u16* ldsA0 = As + wave * 512;             // wave-uniform bases
    const u16* ldsA1 = As + 2048 + wave * 512;
    const u16* ldsB0 = Bs + wave * 512;
    const u16* ldsB1 = Bs + 2048 + wave * 512;

    f32x4 acc[4][4] = {};

    for (int k0 = 0; k0 < HID_; k0 += BK_) {
        __syncthreads();
        gll16(Xb + (size_t)(i0 + grow) * HID_ + k0 + gcol, ldsA0);
        gll16(Xb + (size_t)(i0 + 64 + grow) * HID_ + k0 + gcol, ldsA1);
        gll16(Wb + (size_t)(j0 + grow) * HID_ + k0 + gcol, ldsB0);
        gll16(Wb + (size_t)(j0 + 64 + grow) * HID_ + k0 + gcol, ldsB1);
        __syncthreads();

        bf16x8 af[4], bfr[4];
        #pragma unroll
        for (int mt = 0; mt < 4; mt++)
            af[mt] = ld8(&As[(wr * 64 + mt * 16 + l16) * BK_ + quad * 8]);
        #pragma unroll
        for (int nt = 0; nt < 4; nt++)
            bfr[nt] = ld8(&Bs[(wc * 64 + nt * 16 + l16) * BK_ + quad * 8]);
        #pragma unroll
        for (int mt = 0; mt < 4; mt++)
            #pragma unroll
            for (int nt = 0; nt < 4; nt++)
                acc[mt][nt] = __builtin_amdgcn_mfma_f32_16x16x32_bf16(af[mt], bfr[nt], acc[mt][nt], 0, 0, 0);
    }

    const int which = j0 >> 10;                     // block-uniform
    const float* bias = which == 0 ? bq : which == 1 ? bk : bv;
    u16* Y            = which == 0 ? Q  : which == 1 ? K  : V;
    const float scl   = which == 0 ? C2_ : 1.0f;    // pre-scale Q into log2 domain

    // bounce buffer: 4 waves x 2048 u16 (4 KB each) reusing As/Bs
    u16* bb = (wave < 2) ? (As + wave * 2048) : (Bs + (wave - 2) * 2048);

    #pragma unroll
    for (int p = 0; p < 2; p++) {
        __syncthreads();
        #pragma unroll
        for (int t2 = 0; t2 < 2; t2++) {
            const int nt = 2 * p + t2;
            const int j  = j0 + wc * 64 + nt * 16 + l16;
            const int jj = j & 1023;
            const float bv_ = bias[jj];
            #pragma unroll
            for (int mt = 0; mt < 4; mt++)
                #pragma unroll
                for (int r = 0; r < 4; r++) {
                    const int row = mt * 16 + quad * 4 + r;   // 0..63
                    const int col = t2 * 16 + l16;            // 0..31
                    const u16 val = f2bf((acc[mt][nt][r] + bv_) * scl);
                    if (which == 2)
                        bb[col * 64 + (row ^ ((col & 7) << 3))] = val;      // transposed
                    else
                        bb[row * 32 + (col ^ ((row & 0xC) << 1))] = val;    // row-major
                }
        }
        __syncthreads();
        #pragma unroll
        for (int k = 0; k < 4; k++) {
            const int c = lane + 64 * k;   // 0..255 chunks of this wave's 4 KB
            if (which == 2) {
                const int col  = c >> 3;
                const int row0 = (c & 7) * 8;
                bf16x8 v = ld8(&bb[col * 64 + (row0 ^ ((col & 7) << 3))]);
                const int j  = j0 + wc * 64 + p * 32 + col;
                const int jj = j & 1023;
                const int h = jj >> 6, d = jj & 63;
                const int i = i0 + wr * 64 + row0;
                const int b = i >> 11, s = i & (S_ - 1);
                *(bf16x8*)&Y[((size_t)(b * NH_ + h) * HD_ + d) * S_ + s] = v;
            } else {
                const int row  = c >> 2;
                const int col0 = (c & 3) * 8;
                bf16x8 v = ld8(&bb[row * 32 + (col0 ^ ((row & 0xC) << 1))]);
                const int j  = j0 + wc * 64 + p * 32 + col0;
                const int jj = j & 1023;
                const int h = jj >> 6, d = jj & 63;
                const int i = i0 + wr * 64 + row;
                const int b = i >> 11, s = i & (S_ - 1);
                *(bf16x8*)&Y[(((size_t)(b * NH_ + h) * S_ + s) * HD_) + d] = v;
            }
        }
    }
}

// ---------------------------------------------------------------------------
// Stage 2: attention — R8 structure with two VALU deletions:
// (a) Q is pre-scaled by C2 -> QK^T output is already the exp2 argument
//     (no per-element scale mul);
// (b) denominator accumulated on the MATRIX pipe: lacc = mfma(pf, ones, lacc)
//     (pf already loaded for PV; B = bf16 1.0 fragment). lacc[r] lands in the
//     same C-layout as oacc -> invl = hw/lacc directly, no end shuffles.
// ---------------------------------------------------------------------------
__global__ __launch_bounds__(256) void attn(
    const u16* __restrict__ Q, const u16* __restrict__ K, const u16* __restrict__ Vt,
    const float* __restrict__ mask, const float* __restrict__ hw,
    const unsigned* __restrict__ mflag,
    float* __restrict__ ctx, float* __restrict__ ml)
{
    __shared__ __align__(16) u16 Ks[2][64 * 64];   // 16 KB  [key][d], swizzled
    __shared__ __align__(16) u16 Vs[2][64 * 64];   // 16 KB  [d][key], swizzled
    __shared__ __align__(16) u16 Pl[4][16 * 64];   //  8 KB  per-wave P, swizzled

    const int usemask = (mflag[0] != 0);

    const int tid  = threadIdx.x;
    const int wave = tid >> 6;
    const int lane = tid & 63;
    const int l16  = lane & 15;
    const int quad = lane >> 4;
    const int x7   = l16 & 7;

    // XCD-aware remap: 4 whole (b,h) per XCD so K/V^T stay L2-resident.
    const int lin = blockIdx.x + 32 * (blockIdx.y + 16 * blockIdx.z);
    const int xcd = lin & 7, jj = lin >> 3;
    const int qb  = jj & 31;
    const int hb  = xcd * 4 + (jj >> 5);
    const int h   = hb & 15, b = hb >> 4;
    const int bh  = b * NH_ + h;

    const u16* Qh  = Q  + (size_t)bh * S_ * HD_;
    const u16* Kh  = K  + (size_t)bh * S_ * HD_;
    const u16* Vth = Vt + (size_t)bh * HD_ * S_;   // [d][s]
    const float* Mb = mask + (size_t)b * S_ * S_;

    const int q0 = qb * 64 + wave * 16;

    bf16x8 qf0 = ld8(Qh + (size_t)(q0 + l16) * HD_ + quad * 8);
    bf16x8 qf1 = ld8(Qh + (size_t)(q0 + l16) * HD_ + 32 + quad * 8);

    // constant bf16 1.0 fragment for the denominator MFMA
    bf16x8 ones;
    #pragma unroll
    for (int e = 0; e < 8; e++) ones[e] = (short)0x3F80;

    f32x4 oacc[4] = {};
    f32x4 lacc = {};                    // denominator, C-layout (row=quad*4+r)

    // staging geometry: thread covers 16B slots {tid, tid+256} of each tile
    const int srow = tid >> 3;
    const int sch  = tid & 7;
    const int ssw  = (sch ^ (srow & 7)) * 8;
    const int sL   = srow * 64 + ssw;

    {   // prologue: stage tile 0
        bf16x8 k0 = ld8(Kh + (size_t)srow * HD_ + sch * 8);
        bf16x8 k1 = ld8(Kh + (size_t)(srow + 32) * HD_ + sch * 8);
        bf16x8 v0 = ld8(Vth + (size_t)srow * S_ + sch * 8);
        bf16x8 v1 = ld8(Vth + (size_t)(srow + 32) * S_ + sch * 8);
        *(bf16x8*)&Ks[0][sL] = k0; *(bf16x8*)&Ks[0][sL + 2048] = k1;
        *(bf16x8*)&Vs[0][sL] = v0; *(bf16x8*)&Vs[0][sL + 2048] = v1;
    }
    __syncthreads();

    for (int t = 0; t < 32; ++t) {
        const int cur = t & 1;
        const int kt  = t * 64;
        const u16* Kb = Ks[cur];
        const u16* Vb = Vs[cur];

        // issue next-tile global loads EARLY
        bf16x8 kr0, kr1, vr0, vr1;
        if (t < 31) {
            const u16* Kg = Kh + (size_t)(kt + 64) * HD_;
            kr0 = ld8(Kg + (size_t)srow * HD_ + sch * 8);
            kr1 = ld8(Kg + (size_t)(srow + 32) * HD_ + sch * 8);
            vr0 = ld8(Vth + (size_t)srow * S_ + kt + 64 + sch * 8);
            vr1 = ld8(Vth + (size_t)(srow + 32) * S_ + kt + 64 + sch * 8);
        }

        // --- S^T = K Q^T (swapped operands; Q pre-scaled -> log2 domain) ---
        f32x4 sacc[4] = {};
        __builtin_amdgcn_s_setprio(1);
        #pragma unroll
        for (int nb = 0; nb < 4; nb++) {
            const int base = (nb * 16 + l16) * 64;
            bf16x8 k0 = ld8(&Kb[base + ((quad ^ x7) * 8)]);
            bf16x8 k1 = ld8(&Kb[base + (((quad + 4) ^ x7) * 8)]);
            sacc[nb] = __builtin_amdgcn_mfma_f32_16x16x32_bf16(k0, qf0, sacc[nb], 0, 0, 0);
            sacc[nb] = __builtin_amdgcn_mfma_f32_16x16x32_bf16(k1, qf1, sacc[nb], 0, 0, 0);
        }
        __builtin_amdgcn_s_setprio(0);

        // --- deferred softmax: p = 2^(min(s, CLAMP2)), native v_exp ---
        float p[4][4];
        if (usemask) {
            const float* Mrow = Mb + (size_t)(q0 + l16) * S_ + kt;
            #pragma unroll
            for (int nb = 0; nb < 4; nb++) {
                const float4 mv = *(const float4*)(Mrow + nb * 16 + quad * 4);
                p[nb][0] = ex2(fminf(fmaf(mv.x, LOG2E_, sacc[nb][0]), CLAMP2_));
                p[nb][1] = ex2(fminf(fmaf(mv.y, LOG2E_, sacc[nb][1]), CLAMP2_));
                p[nb][2] = ex2(fminf(fmaf(mv.z, LOG2E_, sacc[nb][2]), CLAMP2_));
                p[nb][3] = ex2(fminf(fmaf(mv.w, LOG2E_, sacc[nb][3]), CLAMP2_));
            }
        } else {
            #pragma unroll
            for (int nb = 0; nb < 4; nb++)
                #pragma unroll
                for (int r = 0; r < 4; r++)
                    p[nb][r] = ex2(fminf(sacc[nb][r], CLAMP2_));
        }

        // --- P -> bf16 pairs -> LDS row l16, 4x uint2 (R6 pattern) ---
        {
            u16* prow = &Pl[wave][l16 * 64];
            #pragma unroll
            for (int nb = 0; nb < 4; nb++) {
                uint2 w;
                w.x = cvtpk(p[nb][0], p[nb][1]);
                w.y = cvtpk(p[nb][2], p[nb][3]);
                const int ch  = 2 * nb + (quad >> 1);
                const int off = ((ch ^ x7) << 3) + ((quad & 1) << 2);
                *(uint2*)&prow[off] = w;
            }
        }

        // --- O += P @ V ; l += P @ 1 (matrix pipe, pf reused) ---
        __builtin_amdgcn_s_setprio(1);
        #pragma unroll
        for (int kb = 0; kb < 2; kb++) {
            const int c = kb * 4 + quad;
            bf16x8 pf = ld8(&Pl[wave][l16 * 64 + ((c ^ x7) * 8)]);
            lacc = __builtin_amdgcn_mfma_f32_16x16x32_bf16(pf, ones, lacc, 0, 0, 0);
            #pragma unroll
            for (int db = 0; db < 4; db++) {
                bf16x8 vf = ld8(&Vb[(db * 16 + l16) * 64 + ((c ^ x7) * 8)]);
                oacc[db] = __builtin_amdgcn_mfma_f32_16x16x32_bf16(pf, vf, oacc[db], 0, 0, 0);
            }
        }
        __builtin_amdgcn_s_setprio(0);

        // --- write next tile to the other buffer, then sync ---
        if (t < 31) {
            u16* Kd = Ks[cur ^ 1]; u16* Vd = Vs[cur ^ 1];
            *(bf16x8*)&Kd[sL] = kr0; *(bf16x8*)&Kd[sL + 2048] = kr1;
            *(bf16x8*)&Vd[sL] = vr0; *(bf16x8*)&Vd[sL + 2048] = vr1;
        }
        __syncthreads();
    }

    // --- epilogue: lacc[r] is l for q-row quad*4+r (same layout as oacc) ---
    const float hwf = hw[h];
    float invl[4];
    #pragma unroll
    for (int r = 0; r < 4; r++) invl[r] = hwf / lacc[r];

    #pragma unroll
    for (int db = 0; db < 4; db++)
        #pragma unroll
        for (int r = 0; r < 4; r++) {
            const int qrow = q0 + quad * 4 + r;
            ctx[((size_t)(b * S_ + qrow)) * HID_ + h * HD_ + db * 16 + l16] =
                oacc[db][r] * invl[r];
        }

    // per-row l for the probs kernel (rows quad*4+r, replicated across l16)
    if (qb >= 30 && l16 == 0) {
        #pragma unroll
        for (int r = 0; r < 4; r++)
            ml[bh * 128 + (q0 - 1920) + quad * 4 + r] = lacc[r];
    }
}

// ---------------------------------------------------------------------------
// Stage 3: probs — recompute QK^T for the last 128 q rows (Q pre-scaled),
// swapped operands, float4 stores of normalized probs. Grid (16,16,2).
// ---------------------------------------------------------------------------
__global__ __launch_bounds__(256) void probs_qk(
    const u16* __restrict__ Q, const u16* __restrict__ K,
    const float* __restrict__ mask, const float* __restrict__ hw,
    const unsigned* __restrict__ mflag, const float* __restrict__ ml,
    float* __restrict__ probs_out)
{
    const int usemask = (mflag[0] != 0);

    const int tid  = threadIdx.x;
    const int wave = tid >> 6;
    const int lane = tid & 63;
    const int l16  = lane & 15;
    const int quad = lane >> 4;

    const int rt = blockIdx.x & 1;          // row-tile (64 rows)
    const int ks = blockIdx.x >> 1;         // key-eighth (256 keys)
    const int h  = blockIdx.y;
    const int b  = blockIdx.z;
    const int bh = b * NH_ + h;

    const u16* Qh = Q + (size_t)bh * S_ * HD_;
    const u16* Kh = K + (size_t)bh * S_ * HD_;
    const float* Mb = mask + (size_t)b * S_ * S_;

    const int q0   = 1920 + rt * 64 + wave * 16;
    const int qrow = q0 + l16;              // this lane's q row

    bf16x8 qf0 = ld8(Qh + (size_t)qrow * HD_ + quad * 8);
    bf16x8 qf1 = ld8(Qh + (size_t)qrow * HD_ + 32 + quad * 8);

    const float invl = hw[h] / ml[bh * 128 + (qrow - 1920)];
    float* Prow = probs_out + ((size_t)bh * 128 + (qrow - 1920)) * S_;
    const float* Mrow = Mb + (size_t)qrow * S_;

    for (int kt = ks * 256; kt < ks * 256 + 256; kt += 64) {
        f32x4 sacc[4] = {};
        #pragma unroll
        for (int nb = 0; nb < 4; nb++) {
            const u16* krow = Kh + (size_t)(kt + nb * 16 + l16) * HD_ + quad * 8;
            bf16x8 kA0 = ld8(krow);
            bf16x8 kA1 = ld8(krow + 32);
            sacc[nb] = __builtin_amdgcn_mfma_f32_16x16x32_bf16(kA0, qf0, sacc[nb], 0, 0, 0);
            sacc[nb] = __builtin_amdgcn_mfma_f32_16x16x32_bf16(kA1, qf1, sacc[nb], 0, 0, 0);
        }
        #pragma unroll
        for (int nb = 0; nb < 4; nb++) {
            const int kb0 = kt + nb * 16 + quad * 4;   // 4 contiguous keys
            float4 v;
            if (usemask) {
                const float4 mv = *(const float4*)&Mrow[kb0];
                v.x = ex2(fminf(fmaf(mv.x, LOG2E_, sacc[nb][0]), CLAMP2_)) * invl;
                v.y = ex2(fminf(fmaf(mv.y, LOG2E_, sacc[nb][1]), CLAMP2_)) * invl;
                v.z = ex2(fminf(fmaf(mv.z, LOG2E_, sacc[nb][2]), CLAMP2_)) * invl;
                v.w = ex2(fminf(fmaf(mv.w, LOG2E_, sacc[nb][3]), CLAMP2_)) * invl;
            } else {
                v.x = ex2(fminf(sacc[nb][0], CLAMP2_)) * invl;
                v.y = ex2(fminf(sacc[nb][1], CLAMP2_)) * invl;
                v.z = ex2(fminf(sacc[nb][2], CLAMP2_)) * invl;
                v.w = ex2(fminf(sacc[nb][3], CLAMP2_)) * invl;
            }
            *(float4*)&Prow[kb0] = v;
        }
    }
}

// ---------------------------------------------------------------------------
extern "C" void kernel_launch(void* const* d_in, const int* in_sizes, int n_in,
                              void* d_out, int out_size, void* d_ws, size_t ws_size,
                              hipStream_t stream)
{
    const void* X = 0; const void* mask = 0; const void* hw = 0;
    const void* Wm[3] = {0, 0, 0}; const void* bm[3] = {0, 0, 0};
    int wi = 0, bi = 0;
    for (int i = 0; i < n_in; i++) {
        switch (in_sizes[i]) {
            case 4194304: X = d_in[i]; break;
            case 8388608: mask = d_in[i]; break;
            case 1048576: if (wi < 3) Wm[wi++] = d_in[i]; break;
            case 1024:    if (bi < 3) bm[bi++] = d_in[i]; break;
            case 16:      hw = d_in[i]; break;
            default: break;
        }
    }
    if (!X || !mask || wi != 3 || bi != 3 || !hw) {
        X = d_in[0]; mask = d_in[1];
        Wm[0] = d_in[2]; bm[0] = d_in[3];
        Wm[1] = d_in[4]; bm[1] = d_in[5];
        Wm[2] = d_in[6]; bm[2] = d_in[7];
        hw = d_in[8];
    }

    u16* Q  = (u16*)d_ws;                    // 8 MB
    u16* Kw = Q + 4194304ull;                // 8 MB
    u16* Vw = Kw + 4194304ull;               // 8 MB (stored transposed per head)
    u16* Xb = Vw + 4194304ull;               // 8 MB
    u16* Wb = Xb + 4194304ull;               // 6 MB
    unsigned* flag = (unsigned*)(Wb + 3145728ull);   // 4 B @ 38 MB
    float* ml = (float*)(flag + 64);                 // 16 KB (l per probs row)

    float* ctx   = (float*)d_out;
    float* probs = ctx + (size_t)B_ * S_ * HID_;

    hipMemsetAsync(flag, 0, 4, stream);
    conv_scan<<<7680, 256, 0, stream>>>(
        (const float*)X, (const float*)Wm[0], (const float*)Wm[1], (const float*)Wm[2],
        (const unsigned*)mask, Xb, Wb, flag);

    qkv_mfma<<<dim3(32, 24), dim3(256), 0, stream>>>(
        Xb, Wb, (const float*)bm[0], (const float*)bm[1], (const float*)bm[2],
        Q, Kw, Vw);

    attn<<<dim3(32, 16, 2), dim3(256), 0, stream>>>(
        Q, Kw, Vw, (const float*)mask, (const float*)hw, flag, ctx, ml);

    probs_qk<<<dim3(16, 16, 2), dim3(256), 0, stream>>>(
        Q, Kw, (const float*)mask, (const float*)hw, flag, ml, probs);
}

// Round 10
// 224.291 us; speedup vs baseline: 1.0379x; 1.0379x over previous
//
#include <hip/hip_runtime.h>

typedef unsigned short u16;
typedef __attribute__((ext_vector_type(8))) short bf16x8;   // 8 bf16 = 4 VGPRs
typedef __attribute__((ext_vector_type(4))) float f32x4;

#define B_   2
#define S_   2048
#define HID_ 1024
#define NH_  16
#define HD_  64
#define SCALE_ 0.125f            // 1/sqrt(64)
#define C2_   0.18033688011112f  // SCALE * log2(e)
#define CLAMP2_ 115.4156035f     // 80 * log2(e)
#define LOG2E_ 1.4426950408890f

__device__ __forceinline__ u16 f2bf(float f) {
    union { float f; unsigned int i; } v; v.f = f;
    unsigned int r = v.i + 0x7fffu + ((v.i >> 16) & 1u);   // RNE
    return (u16)(r >> 16);
}
__device__ __forceinline__ bf16x8 ld8(const u16* p) {
    return *reinterpret_cast<const bf16x8*>(p);
}
// packed fp32x2 -> bf16x2 (RNE, same rounding as f2bf), src0 in low half
__device__ __forceinline__ unsigned cvtpk(float lo, float hi) {
    unsigned r;
    asm("v_cvt_pk_bf16_f32 %0, %1, %2" : "=v"(r) : "v"(lo), "v"(hi));
    return r;
}
// native 2^x — single v_exp_f32 (exp2f is the slow libm-precise path)
__device__ __forceinline__ float ex2(float x) {
    float r;
    asm("v_exp_f32 %0, %1" : "=v"(r) : "v"(x));
    return r;
}
// async global->LDS, 16B per lane; l must be wave-uniform (HW adds lane*16)
__device__ __forceinline__ void gll16(const u16* g, const u16* l) {
    __builtin_amdgcn_global_load_lds(
        (const __attribute__((address_space(1))) unsigned int*)g,
        (__attribute__((address_space(3))) unsigned int*)l, 16, 0, 0);
}

// ---------------------------------------------------------------------------
// Stage 0: fused fp32->bf16 convert (blocks [0,3584)) + mask scan (blocks
// [3584,7680)). Conversions via cvtpk (RNE-identical, half the VALU).
// ---------------------------------------------------------------------------
__global__ __launch_bounds__(256) void conv_scan(
    const float* __restrict__ X, const float* __restrict__ W0,
    const float* __restrict__ W1, const float* __restrict__ W2,
    const unsigned* __restrict__ m,
    u16* __restrict__ Xb, u16* __restrict__ Wb, unsigned* __restrict__ flag)
{
    const int bx = blockIdx.x;
    if (bx < 3584) {
        const size_t s = (size_t)bx * 256 + threadIdx.x;
        const float* src; u16* dst; size_t off;
        if (s < 524288) { src = X; dst = Xb; off = s * 8; }
        else {
            const size_t t = s - 524288;
            const int w = (int)(t >> 17);
            off = (t & 131071) * 8;
            src = w == 0 ? W0 : w == 1 ? W1 : W2;
            dst = Wb + (size_t)w * 1048576;
        }
        f32x4 a = *(const f32x4*)(src + off);
        f32x4 b = *(const f32x4*)(src + off + 4);
        uint4 r;
        r.x = cvtpk(a[0], a[1]);
        r.y = cvtpk(a[2], a[3]);
        r.z = cvtpk(b[0], b[1]);
        r.w = cvtpk(b[2], b[3]);
        *(uint4*)(dst + off) = r;
    } else {
        const size_t i = ((size_t)(bx - 3584) * 256 + threadIdx.x) * 8;
        const uint4* p = (const uint4*)(m + i);
        uint4 a = p[0], b = p[1];
        const unsigned M = 0x7fffffffu;
        unsigned v = (a.x & M) | (a.y & M) | (a.z & M) | (a.w & M)
                   | (b.x & M) | (b.y & M) | (b.z & M) | (b.w & M);
        if (v) atomicOr(flag, 1u);
    }
}

// ---------------------------------------------------------------------------
// Stage 1: Y = Xb @ Wb^T + bias — R5-verified structure (BK=32, single-
// buffered gll16). Q pre-scaled by C2 (log2 domain). Epilogue conversions
// via cvtpk pairs (rows r,r+1 share a cvt; same RNE bits). V transposed.
// ---------------------------------------------------------------------------
#define BK_ 32

__global__ __launch_bounds__(256) void qkv_mfma(
    const u16* __restrict__ Xb, const u16* __restrict__ Wb,
    const float* __restrict__ bq, const float* __restrict__ bk,
    const float* __restrict__ bv,
    u16* __restrict__ Q, u16* __restrict__ K, u16* __restrict__ V)
{
    __shared__ __align__(16) u16 As[128 * BK_];   // 8 KB, linear row-major
    __shared__ __align__(16) u16 Bs[128 * BK_];   // 8 KB

    const int tid  = threadIdx.x;
    const int wave = tid >> 6;
    const int lane = tid & 63;
    const int l16  = lane & 15;
    const int quad = lane >> 4;
    const int wr   = wave >> 1, wc = wave & 1;

    const int i0 = blockIdx.x * 128;
    const int j0 = blockIdx.y * 128;

    const int grow = (wave * 64 + lane) >> 2;       // 0..63
    const int gcol = (lane & 3) * 8;
    const u16* ldsA0 = As + wave * 512;             // wave-uniform bases
    const u16* ldsA1 = As + 2048 + wave * 512;
    const u16* ldsB0 = Bs + wave * 512;
    const u16* ldsB1 = Bs + 2048 + wave * 512;

    f32x4 acc[4][4] = {};

    for (int k0 = 0; k0 < HID_; k0 += BK_) {
        __syncthreads();
        gll16(Xb + (size_t)(i0 + grow) * HID_ + k0 + gcol, ldsA0);
        gll16(Xb + (size_t)(i0 + 64 + grow) * HID_ + k0 + gcol, ldsA1);
        gll16(Wb + (size_t)(j0 + grow) * HID_ + k0 + gcol, ldsB0);
        gll16(Wb + (size_t)(j0 + 64 + grow) * HID_ + k0 + gcol, ldsB1);
        __syncthreads();

        bf16x8 af[4], bfr[4];
        #pragma unroll
        for (int mt = 0; mt < 4; mt++)
            af[mt] = ld8(&As[(wr * 64 + mt * 16 + l16) * BK_ + quad * 8]);
        #pragma unroll
        for (int nt = 0; nt < 4; nt++)
            bfr[nt] = ld8(&Bs[(wc * 64 + nt * 16 + l16) * BK_ + quad * 8]);
        #pragma unroll
        for (int mt = 0; mt < 4; mt++)
            #pragma unroll
            for (int nt = 0; nt < 4; nt++)
                acc[mt][nt] = __builtin_amdgcn_mfma_f32_16x16x32_bf16(af[mt], bfr[nt], acc[mt][nt], 0, 0, 0);
    }

    const int which = j0 >> 10;                     // block-uniform
    const float* bias = which == 0 ? bq : which == 1 ? bk : bv;
    u16* Y            = which == 0 ? Q  : which == 1 ? K  : V;
    const float scl   = which == 0 ? C2_ : 1.0f;    // pre-scale Q into log2 domain

    // bounce buffer: 4 waves x 2048 u16 (4 KB each) reusing As/Bs
    u16* bb = (wave < 2) ? (As + wave * 2048) : (Bs + (wave - 2) * 2048);

    #pragma unroll
    for (int p = 0; p < 2; p++) {
        __syncthreads();
        #pragma unroll
        for (int t2 = 0; t2 < 2; t2++) {
            const int nt = 2 * p + t2;
            const int j  = j0 + wc * 64 + nt * 16 + l16;
            const int jj = j & 1023;
            const float bv_ = bias[jj];
            const int col = t2 * 16 + l16;            // 0..31
            #pragma unroll
            for (int mt = 0; mt < 4; mt++)
                #pragma unroll
                for (int rp = 0; rp < 2; rp++) {
                    const int row0 = mt * 16 + quad * 4 + 2 * rp;   // even
                    const unsigned w = cvtpk((acc[mt][nt][2 * rp]     + bv_) * scl,
                                             (acc[mt][nt][2 * rp + 1] + bv_) * scl);
                    if (which == 2) {
                        bb[col * 64 + ( row0      ^ ((col & 7) << 3))] = (u16)w;
                        bb[col * 64 + ((row0 + 1) ^ ((col & 7) << 3))] = (u16)(w >> 16);
                    } else {
                        // (row0&0xC)==((row0+1)&0xC): same col swizzle
                        const int cs = col ^ ((row0 & 0xC) << 1);
                        bb[ row0      * 32 + cs] = (u16)w;
                        bb[(row0 + 1) * 32 + cs] = (u16)(w >> 16);
                    }
                }
        }
        __syncthreads();
        #pragma unroll
        for (int k = 0; k < 4; k++) {
            const int c = lane + 64 * k;   // 0..255 chunks of this wave's 4 KB
            if (which == 2) {
                const int col  = c >> 3;
                const int row0 = (c & 7) * 8;
                bf16x8 v = ld8(&bb[col * 64 + (row0 ^ ((col & 7) << 3))]);
                const int j  = j0 + wc * 64 + p * 32 + col;
                const int jj = j & 1023;
                const int h = jj >> 6, d = jj & 63;
                const int i = i0 + wr * 64 + row0;
                const int b = i >> 11, s = i & (S_ - 1);
                *(bf16x8*)&Y[((size_t)(b * NH_ + h) * HD_ + d) * S_ + s] = v;
            } else {
                const int row  = c >> 2;
                const int col0 = (c & 3) * 8;
                bf16x8 v = ld8(&bb[row * 32 + (col0 ^ ((row & 0xC) << 1))]);
                const int j  = j0 + wc * 64 + p * 32 + col0;
                const int jj = j & 1023;
                const int h = jj >> 6, d = jj & 63;
                const int i = i0 + wr * 64 + row;
                const int b = i >> 11, s = i & (S_ - 1);
                *(bf16x8*)&Y[(((size_t)(b * NH_ + h) * S_ + s) * HD_) + d] = v;
            }
        }
    }
}

// ---------------------------------------------------------------------------
// Stage 2: attention — R9 structure (swapped QK^T in log2 domain, cvtpk
// P-store, denominator on matrix pipe) with staging moved to global_load_lds:
// pre-swizzled per-lane global source (chunk ^= row&7 involution, m173
// pattern) + linear LDS dest. Removes 8 reg-loads + 4 ds_writes + 16 staging
// VGPRs per tile; loads fly async from loop top, drain at the barrier (m151:
// gll16 staging measured +35% vs reg-staging on identical tiles).
// ---------------------------------------------------------------------------
__global__ __launch_bounds__(256) void attn(
    const u16* __restrict__ Q, const u16* __restrict__ K, const u16* __restrict__ Vt,
    const float* __restrict__ mask, const float* __restrict__ hw,
    const unsigned* __restrict__ mflag,
    float* __restrict__ ctx, float* __restrict__ ml)
{
    __shared__ __align__(16) u16 Ks[2][64 * 64];   // 16 KB  [key][d], swizzled
    __shared__ __align__(16) u16 Vs[2][64 * 64];   // 16 KB  [d][key], swizzled
    __shared__ __align__(16) u16 Pl[4][16 * 64];   //  8 KB  per-wave P, swizzled

    const int usemask = (mflag[0] != 0);

    const int tid  = threadIdx.x;
    const int wave = tid >> 6;
    const int lane = tid & 63;
    const int l16  = lane & 15;
    const int quad = lane >> 4;
    const int x7   = l16 & 7;

    // XCD-aware remap: 4 whole (b,h) per XCD so K/V^T stay L2-resident.
    const int lin = blockIdx.x + 32 * (blockIdx.y + 16 * blockIdx.z);
    const int xcd = lin & 7, jj = lin >> 3;
    const int qb  = jj & 31;
    const int hb  = xcd * 4 + (jj >> 5);
    const int h   = hb & 15, b = hb >> 4;
    const int bh  = b * NH_ + h;

    const u16* Qh  = Q  + (size_t)bh * S_ * HD_;
    const u16* Kh  = K  + (size_t)bh * S_ * HD_;
    const u16* Vth = Vt + (size_t)bh * HD_ * S_;   // [d][s]
    const float* Mb = mask + (size_t)b * S_ * S_;

    const int q0 = qb * 64 + wave * 16;

    bf16x8 qf0 = ld8(Qh + (size_t)(q0 + l16) * HD_ + quad * 8);
    bf16x8 qf1 = ld8(Qh + (size_t)(q0 + l16) * HD_ + 32 + quad * 8);

    // constant bf16 1.0 fragment for the denominator MFMA
    bf16x8 ones;
    #pragma unroll
    for (int e = 0; e < 8; e++) ones[e] = (short)0x3F80;

    f32x4 oacc[4] = {};
    f32x4 lacc = {};                    // denominator, C-layout (row=quad*4+r)

    // gll staging geometry: unit u covers tile rows u*8..u*8+7 (8 x 128 B =
    // 1 KB = one wave-wide gll16). lane's global chunk pre-swizzled by row&7
    // (= lane>>3) so the linear LDS write lands in the swizzled layout.
    const int lrow = lane >> 3;                       // row&7
    const int lchk = ((lane & 7) ^ lrow) * 8;         // swizzled u16 chunk off
    const int u0   = wave * 2;                        // units u0, u0+1

    {   // prologue: stage tile 0
        gll16(Kh  + (size_t)(u0 * 8 +     lrow) * HD_ + lchk, &Ks[0][u0 * 512]);
        gll16(Kh  + (size_t)(u0 * 8 + 8 + lrow) * HD_ + lchk, &Ks[0][u0 * 512 + 512]);
        gll16(Vth + (size_t)(u0 * 8 +     lrow) * S_  + lchk, &Vs[0][u0 * 512]);
        gll16(Vth + (size_t)(u0 * 8 + 8 + lrow) * S_  + lchk, &Vs[0][u0 * 512 + 512]);
    }
    __syncthreads();

    for (int t = 0; t < 32; ++t) {
        const int cur = t & 1;
        const int kt  = t * 64;
        const u16* Kb = Ks[cur];
        const u16* Vb = Vs[cur];

        // issue next-tile gll16 EARLY (async; drained by the ending barrier)
        if (t < 31) {
            const u16* Kg = Kh + (size_t)(kt + 64) * HD_;
            gll16(Kg  + (size_t)(u0 * 8 +     lrow) * HD_ + lchk, &Ks[cur ^ 1][u0 * 512]);
            gll16(Kg  + (size_t)(u0 * 8 + 8 + lrow) * HD_ + lchk, &Ks[cur ^ 1][u0 * 512 + 512]);
            gll16(Vth + (size_t)(u0 * 8 +     lrow) * S_ + kt + 64 + lchk, &Vs[cur ^ 1][u0 * 512]);
            gll16(Vth + (size_t)(u0 * 8 + 8 + lrow) * S_ + kt + 64 + lchk, &Vs[cur ^ 1][u0 * 512 + 512]);
        }

        // --- S^T = K Q^T (swapped operands; Q pre-scaled -> log2 domain) ---
        f32x4 sacc[4] = {};
        __builtin_amdgcn_s_setprio(1);
        #pragma unroll
        for (int nb = 0; nb < 4; nb++) {
            const int base = (nb * 16 + l16) * 64;
            bf16x8 k0 = ld8(&Kb[base + ((quad ^ x7) * 8)]);
            bf16x8 k1 = ld8(&Kb[base + (((quad + 4) ^ x7) * 8)]);
            sacc[nb] = __builtin_amdgcn_mfma_f32_16x16x32_bf16(k0, qf0, sacc[nb], 0, 0, 0);
            sacc[nb] = __builtin_amdgcn_mfma_f32_16x16x32_bf16(k1, qf1, sacc[nb], 0, 0, 0);
        }
        __builtin_amdgcn_s_setprio(0);

        // --- deferred softmax: p = 2^(min(s, CLAMP2)), native v_exp ---
        float p[4][4];
        if (usemask) {
            const float* Mrow = Mb + (size_t)(q0 + l16) * S_ + kt;
            #pragma unroll
            for (int nb = 0; nb < 4; nb++) {
                const float4 mv = *(const float4*)(Mrow + nb * 16 + quad * 4);
                p[nb][0] = ex2(fminf(fmaf(mv.x, LOG2E_, sacc[nb][0]), CLAMP2_));
                p[nb][1] = ex2(fminf(fmaf(mv.y, LOG2E_, sacc[nb][1]), CLAMP2_));
                p[nb][2] = ex2(fminf(fmaf(mv.z, LOG2E_, sacc[nb][2]), CLAMP2_));
                p[nb][3] = ex2(fminf(fmaf(mv.w, LOG2E_, sacc[nb][3]), CLAMP2_));
            }
        } else {
            #pragma unroll
            for (int nb = 0; nb < 4; nb++)
                #pragma unroll
                for (int r = 0; r < 4; r++)
                    p[nb][r] = ex2(fminf(sacc[nb][r], CLAMP2_));
        }

        // --- P -> bf16 pairs -> LDS row l16, 4x uint2 (R6 pattern) ---
        {
            u16* prow = &Pl[wave][l16 * 64];
            #pragma unroll
            for (int nb = 0; nb < 4; nb++) {
                uint2 w;
                w.x = cvtpk(p[nb][0], p[nb][1]);
                w.y = cvtpk(p[nb][2], p[nb][3]);
                const int ch  = 2 * nb + (quad >> 1);
                const int off = ((ch ^ x7) << 3) + ((quad & 1) << 2);
                *(uint2*)&prow[off] = w;
            }
        }

        // --- O += P @ V ; l += P @ 1 (matrix pipe, pf reused) ---
        __builtin_amdgcn_s_setprio(1);
        #pragma unroll
        for (int kb = 0; kb < 2; kb++) {
            const int c = kb * 4 + quad;
            bf16x8 pf = ld8(&Pl[wave][l16 * 64 + ((c ^ x7) * 8)]);
            lacc = __builtin_amdgcn_mfma_f32_16x16x32_bf16(pf, ones, lacc, 0, 0, 0);
            #pragma unroll
            for (int db = 0; db < 4; db++) {
                bf16x8 vf = ld8(&Vb[(db * 16 + l16) * 64 + ((c ^ x7) * 8)]);
                oacc[db] = __builtin_amdgcn_mfma_f32_16x16x32_bf16(pf, vf, oacc[db], 0, 0, 0);
            }
        }
        __builtin_amdgcn_s_setprio(0);

        __syncthreads();   // drains vmcnt (gll16) + lgkm before buffer swap
    }

    // --- epilogue: lacc[r] is l for q-row quad*4+r (same layout as oacc) ---
    const float hwf = hw[h];
    float invl[4];
    #pragma unroll
    for (int r = 0; r < 4; r++) invl[r] = hwf / lacc[r];

    #pragma unroll
    for (int db = 0; db < 4; db++)
        #pragma unroll
        for (int r = 0; r < 4; r++) {
            const int qrow = q0 + quad * 4 + r;
            ctx[((size_t)(b * S_ + qrow)) * HID_ + h * HD_ + db * 16 + l16] =
                oacc[db][r] * invl[r];
        }

    // per-row l for the probs kernel (rows quad*4+r, replicated across l16)
    if (qb >= 30 && l16 == 0) {
        #pragma unroll
        for (int r = 0; r < 4; r++)
            ml[bh * 128 + (q0 - 1920) + quad * 4 + r] = lacc[r];
    }
}

// ---------------------------------------------------------------------------
// Stage 3: probs — recompute QK^T for the last 128 q rows (Q pre-scaled),
// swapped operands, float4 stores of normalized probs. Grid (16,16,2).
// ---------------------------------------------------------------------------
__global__ __launch_bounds__(256) void probs_qk(
    const u16* __restrict__ Q, const u16* __restrict__ K,
    const float* __restrict__ mask, const float* __restrict__ hw,
    const unsigned* __restrict__ mflag, const float* __restrict__ ml,
    float* __restrict__ probs_out)
{
    const int usemask = (mflag[0] != 0);

    const int tid  = threadIdx.x;
    const int wave = tid >> 6;
    const int lane = tid & 63;
    const int l16  = lane & 15;
    const int quad = lane >> 4;

    const int rt = blockIdx.x & 1;          // row-tile (64 rows)
    const int ks = blockIdx.x >> 1;         // key-eighth (256 keys)
    const int h  = blockIdx.y;
    const int b  = blockIdx.z;
    const int bh = b * NH_ + h;

    const u16* Qh = Q + (size_t)bh * S_ * HD_;
    const u16* Kh = K + (size_t)bh * S_ * HD_;
    const float* Mb = mask + (size_t)b * S_ * S_;

    const int q0   = 1920 + rt * 64 + wave * 16;
    const int qrow = q0 + l16;              // this lane's q row

    bf16x8 qf0 = ld8(Qh + (size_t)qrow * HD_ + quad * 8);
    bf16x8 qf1 = ld8(Qh + (size_t)qrow * HD_ + 32 + quad * 8);

    const float invl = hw[h] / ml[bh * 128 + (qrow - 1920)];
    float* Prow = probs_out + ((size_t)bh * 128 + (qrow - 1920)) * S_;
    const float* Mrow = Mb + (size_t)qrow * S_;

    for (int kt = ks * 256; kt < ks * 256 + 256; kt += 64) {
        f32x4 sacc[4] = {};
        #pragma unroll
        for (int nb = 0; nb < 4; nb++) {
            const u16* krow = Kh + (size_t)(kt + nb * 16 + l16) * HD_ + quad * 8;
            bf16x8 kA0 = ld8(krow);
            bf16x8 kA1 = ld8(krow + 32);
            sacc[nb] = __builtin_amdgcn_mfma_f32_16x16x32_bf16(kA0, qf0, sacc[nb], 0, 0, 0);
            sacc[nb] = __builtin_amdgcn_mfma_f32_16x16x32_bf16(kA1, qf1, sacc[nb], 0, 0, 0);
        }
        #pragma unroll
        for (int nb = 0; nb < 4; nb++) {
            const int kb0 = kt + nb * 16 + quad * 4;   // 4 contiguous keys
            float4 v;
            if (usemask) {
                const float4 mv = *(const float4*)&Mrow[kb0];
                v.x = ex2(fminf(fmaf(mv.x, LOG2E_, sacc[nb][0]), CLAMP2_)) * invl;
                v.y = ex2(fminf(fmaf(mv.y, LOG2E_, sacc[nb][1]), CLAMP2_)) * invl;
                v.z = ex2(fminf(fmaf(mv.z, LOG2E_, sacc[nb][2]), CLAMP2_)) * invl;
                v.w = ex2(fminf(fmaf(mv.w, LOG2E_, sacc[nb][3]), CLAMP2_)) * invl;
            } else {
                v.x = ex2(fminf(sacc[nb][0], CLAMP2_)) * invl;
                v.y = ex2(fminf(sacc[nb][1], CLAMP2_)) * invl;
                v.z = ex2(fminf(sacc[nb][2], CLAMP2_)) * invl;
                v.w = ex2(fminf(sacc[nb][3], CLAMP2_)) * invl;
            }
            *(float4*)&Prow[kb0] = v;
        }
    }
}

// ---------------------------------------------------------------------------
extern "C" void kernel_launch(void* const* d_in, const int* in_sizes, int n_in,
                              void* d_out, int out_size, void* d_ws, size_t ws_size,
                              hipStream_t stream)
{
    const void* X = 0; const void* mask = 0; const void* hw = 0;
    const void* Wm[3] = {0, 0, 0}; const void* bm[3] = {0, 0, 0};
    int wi = 0, bi = 0;
    for (int i = 0; i < n_in; i++) {
        switch (in_sizes[i]) {
            case 4194304: X = d_in[i]; break;
            case 8388608: mask = d_in[i]; break;
            case 1048576: if (wi < 3) Wm[wi++] = d_in[i]; break;
            case 1024:    if (bi < 3) bm[bi++] = d_in[i]; break;
            case 16:      hw = d_in[i]; break;
            default: break;
        }
    }
    if (!X || !mask || wi != 3 || bi != 3 || !hw) {
        X = d_in[0]; mask = d_in[1];
        Wm[0] = d_in[2]; bm[0] = d_in[3];
        Wm[1] = d_in[4]; bm[1] = d_in[5];
        Wm[2] = d_in[6]; bm[2] = d_in[7];
        hw = d_in[8];
    }

    u16* Q  = (u16*)d_ws;                    // 8 MB
    u16* Kw = Q + 4194304ull;                // 8 MB
    u16* Vw = Kw + 4194304ull;               // 8 MB (stored transposed per head)
    u16* Xb = Vw + 4194304ull;               // 8 MB
    u16* Wb = Xb + 4194304ull;               // 6 MB
    unsigned* flag = (unsigned*)(Wb + 3145728ull);   // 4 B @ 38 MB
    float* ml = (float*)(flag + 64);                 // 16 KB (l per probs row)

    float* ctx   = (float*)d_out;
    float* probs = ctx + (size_t)B_ * S_ * HID_;

    hipMemsetAsync(flag, 0, 4, stream);
    conv_scan<<<7680, 256, 0, stream>>>(
        (const float*)X, (const float*)Wm[0], (const float*)Wm[1], (const float*)Wm[2],
        (const unsigned*)mask, Xb, Wb, flag);

    qkv_mfma<<<dim3(32, 24), dim3(256), 0, stream>>>(
        Xb, Wb, (const float*)bm[0], (const float*)bm[1], (const float*)bm[2],
        Q, Kw, Vw);

    attn<<<dim3(32, 16, 2), dim3(256), 0, stream>>>(
        Q, Kw, Vw, (const float*)mask, (const float*)hw, flag, ctx, ml);

    probs_qk<<<dim3(16, 16, 2), dim3(256), 0, stream>>>(
        Q, Kw, (const float*)mask, (const float*)hw, flag, ml, probs);
}

// Round 11
// 220.539 us; speedup vs baseline: 1.0556x; 1.0170x over previous
//
#include <hip/hip_runtime.h>

typedef unsigned short u16;
typedef __attribute__((ext_vector_type(8))) short bf16x8;   // 8 bf16 = 4 VGPRs
typedef __attribute__((ext_vector_type(4))) float f32x4;

#define B_   2
#define S_   2048
#define HID_ 1024
#define NH_  16
#define HD_  64
#define SCALE_ 0.125f            // 1/sqrt(64)
#define C2_   0.18033688011112f  // SCALE * log2(e)
#define CLAMP2_ 115.4156035f     // 80 * log2(e)
#define LOG2E_ 1.4426950408890f

__device__ __forceinline__ u16 f2bf(float f) {
    union { float f; unsigned int i; } v; v.f = f;
    unsigned int r = v.i + 0x7fffu + ((v.i >> 16) & 1u);   // RNE
    return (u16)(r >> 16);
}
__device__ __forceinline__ bf16x8 ld8(const u16* p) {
    return *reinterpret_cast<const bf16x8*>(p);
}
// packed fp32x2 -> bf16x2 (RNE, same rounding as f2bf), src0 in low half
__device__ __forceinline__ unsigned cvtpk(float lo, float hi) {
    unsigned r;
    asm("v_cvt_pk_bf16_f32 %0, %1, %2" : "=v"(r) : "v"(lo), "v"(hi));
    return r;
}
// native 2^x — single v_exp_f32 (exp2f is the slow libm-precise path)
__device__ __forceinline__ float ex2(float x) {
    float r;
    asm("v_exp_f32 %0, %1" : "=v"(r) : "v"(x));
    return r;
}
// async global->LDS, 16B per lane; l must be wave-uniform (HW adds lane*16)
__device__ __forceinline__ void gll16(const u16* g, const u16* l) {
    __builtin_amdgcn_global_load_lds(
        (const __attribute__((address_space(1))) unsigned int*)g,
        (__attribute__((address_space(3))) unsigned int*)l, 16, 0, 0);
}

// ---------------------------------------------------------------------------
// Stage 0: fused fp32->bf16 convert (blocks [0,3584)) + mask scan (blocks
// [3584,7680)). Conversions via cvtpk (RNE-identical, half the VALU).
// ---------------------------------------------------------------------------
__global__ __launch_bounds__(256) void conv_scan(
    const float* __restrict__ X, const float* __restrict__ W0,
    const float* __restrict__ W1, const float* __restrict__ W2,
    const unsigned* __restrict__ m,
    u16* __restrict__ Xb, u16* __restrict__ Wb, unsigned* __restrict__ flag)
{
    const int bx = blockIdx.x;
    if (bx < 3584) {
        const size_t s = (size_t)bx * 256 + threadIdx.x;
        const float* src; u16* dst; size_t off;
        if (s < 524288) { src = X; dst = Xb; off = s * 8; }
        else {
            const size_t t = s - 524288;
            const int w = (int)(t >> 17);
            off = (t & 131071) * 8;
            src = w == 0 ? W0 : w == 1 ? W1 : W2;
            dst = Wb + (size_t)w * 1048576;
        }
        f32x4 a = *(const f32x4*)(src + off);
        f32x4 b = *(const f32x4*)(src + off + 4);
        uint4 r;
        r.x = cvtpk(a[0], a[1]);
        r.y = cvtpk(a[2], a[3]);
        r.z = cvtpk(b[0], b[1]);
        r.w = cvtpk(b[2], b[3]);
        *(uint4*)(dst + off) = r;
    } else {
        const size_t i = ((size_t)(bx - 3584) * 256 + threadIdx.x) * 8;
        const uint4* p = (const uint4*)(m + i);
        uint4 a = p[0], b = p[1];
        const unsigned M = 0x7fffffffu;
        unsigned v = (a.x & M) | (a.y & M) | (a.z & M) | (a.w & M)
                   | (b.x & M) | (b.y & M) | (b.z & M) | (b.w & M);
        if (v) atomicOr(flag, 1u);
    }
}

// ---------------------------------------------------------------------------
// Stage 1: Y = Xb @ Wb^T + bias — R5-verified structure (BK=32, single-
// buffered gll16). Q pre-scaled by C2 (log2 domain). Epilogue conversions
// via cvtpk pairs. V transposed. Byte-identical to R10.
// ---------------------------------------------------------------------------
#define BK_ 32

__global__ __launch_bounds__(256) void qkv_mfma(
    const u16* __restrict__ Xb, const u16* __restrict__ Wb,
    const float* __restrict__ bq, const float* __restrict__ bk,
    const float* __restrict__ bv,
    u16* __restrict__ Q, u16* __restrict__ K, u16* __restrict__ V)
{
    __shared__ __align__(16) u16 As[128 * BK_];   // 8 KB, linear row-major
    __shared__ __align__(16) u16 Bs[128 * BK_];   // 8 KB

    const int tid  = threadIdx.x;
    const int wave = tid >> 6;
    const int lane = tid & 63;
    const int l16  = lane & 15;
    const int quad = lane >> 4;
    const int wr   = wave >> 1, wc = wave & 1;

    const int i0 = blockIdx.x * 128;
    const int j0 = blockIdx.y * 128;

    const int grow = (wave * 64 + lane) >> 2;       // 0..63
    const int gcol = (lane & 3) * 8;
    const u16* ldsA0 = As + wave * 512;             // wave-uniform bases
    const u16* ldsA1 = As + 2048 + wave * 512;
    const u16* ldsB0 = Bs + wave * 512;
    const u16* ldsB1 = Bs + 2048 + wave * 512;

    f32x4 acc[4][4] = {};

    for (int k0 = 0; k0 < HID_; k0 += BK_) {
        __syncthreads();
        gll16(Xb + (size_t)(i0 + grow) * HID_ + k0 + gcol, ldsA0);
        gll16(Xb + (size_t)(i0 + 64 + grow) * HID_ + k0 + gcol, ldsA1);
        gll16(Wb + (size_t)(j0 + grow) * HID_ + k0 + gcol, ldsB0);
        gll16(Wb + (size_t)(j0 + 64 + grow) * HID_ + k0 + gcol, ldsB1);
        __syncthreads();

        bf16x8 af[4], bfr[4];
        #pragma unroll
        for (int mt = 0; mt < 4; mt++)
            af[mt] = ld8(&As[(wr * 64 + mt * 16 + l16) * BK_ + quad * 8]);
        #pragma unroll
        for (int nt = 0; nt < 4; nt++)
            bfr[nt] = ld8(&Bs[(wc * 64 + nt * 16 + l16) * BK_ + quad * 8]);
        #pragma unroll
        for (int mt = 0; mt < 4; mt++)
            #pragma unroll
            for (int nt = 0; nt < 4; nt++)
                acc[mt][nt] = __builtin_amdgcn_mfma_f32_16x16x32_bf16(af[mt], bfr[nt], acc[mt][nt], 0, 0, 0);
    }

    const int which = j0 >> 10;                     // block-uniform
    const float* bias = which == 0 ? bq : which == 1 ? bk : bv;
    u16* Y            = which == 0 ? Q  : which == 1 ? K  : V;
    const float scl   = which == 0 ? C2_ : 1.0f;    // pre-scale Q into log2 domain

    // bounce buffer: 4 waves x 2048 u16 (4 KB each) reusing As/Bs
    u16* bb = (wave < 2) ? (As + wave * 2048) : (Bs + (wave - 2) * 2048);

    #pragma unroll
    for (int p = 0; p < 2; p++) {
        __syncthreads();
        #pragma unroll
        for (int t2 = 0; t2 < 2; t2++) {
            const int nt = 2 * p + t2;
            const int j  = j0 + wc * 64 + nt * 16 + l16;
            const int jj = j & 1023;
            const float bv_ = bias[jj];
            const int col = t2 * 16 + l16;            // 0..31
            #pragma unroll
            for (int mt = 0; mt < 4; mt++)
                #pragma unroll
                for (int rp = 0; rp < 2; rp++) {
                    const int row0 = mt * 16 + quad * 4 + 2 * rp;   // even
                    const unsigned w = cvtpk((acc[mt][nt][2 * rp]     + bv_) * scl,
                                             (acc[mt][nt][2 * rp + 1] + bv_) * scl);
                    if (which == 2) {
                        bb[col * 64 + ( row0      ^ ((col & 7) << 3))] = (u16)w;
                        bb[col * 64 + ((row0 + 1) ^ ((col & 7) << 3))] = (u16)(w >> 16);
                    } else {
                        const int cs = col ^ ((row0 & 0xC) << 1);
                        bb[ row0      * 32 + cs] = (u16)w;
                        bb[(row0 + 1) * 32 + cs] = (u16)(w >> 16);
                    }
                }
        }
        __syncthreads();
        #pragma unroll
        for (int k = 0; k < 4; k++) {
            const int c = lane + 64 * k;   // 0..255 chunks of this wave's 4 KB
            if (which == 2) {
                const int col  = c >> 3;
                const int row0 = (c & 7) * 8;
                bf16x8 v = ld8(&bb[col * 64 + (row0 ^ ((col & 7) << 3))]);
                const int j  = j0 + wc * 64 + p * 32 + col;
                const int jj = j & 1023;
                const int h = jj >> 6, d = jj & 63;
                const int i = i0 + wr * 64 + row0;
                const int b = i >> 11, s = i & (S_ - 1);
                *(bf16x8*)&Y[((size_t)(b * NH_ + h) * HD_ + d) * S_ + s] = v;
            } else {
                const int row  = c >> 2;
                const int col0 = (c & 3) * 8;
                bf16x8 v = ld8(&bb[row * 32 + (col0 ^ ((row & 0xC) << 1))]);
                const int j  = j0 + wc * 64 + p * 32 + col0;
                const int jj = j & 1023;
                const int h = jj >> 6, d = jj & 63;
                const int i = i0 + wr * 64 + row;
                const int b = i >> 11, s = i & (S_ - 1);
                *(bf16x8*)&Y[(((size_t)(b * NH_ + h) * S_ + s) * HD_) + d] = v;
            }
        }
    }
}

// ---------------------------------------------------------------------------
// Stage 2: attention, QBLK=128: block owns 128 q-rows, wave owns 32 (two
// 16-row groups a/b at +0/+16). Same K/V staging, barriers, and fragment
// loads now serve 2x the rows — per-row staging traffic, barrier count, and
// K/V LDS reads halve; each k0/k1/vf fragment feeds two MFMAs. Row-swizzle
// key (row&7) is invariant under +16 so all LDS formulas carry over.
// Swapped QK^T in log2 domain, cvtpk P-store, denominator on matrix pipe,
// gll16 staging with pre-swizzled source (R10 pattern).
// ---------------------------------------------------------------------------
__global__ __launch_bounds__(256) void attn(
    const u16* __restrict__ Q, const u16* __restrict__ K, const u16* __restrict__ Vt,
    const float* __restrict__ mask, const float* __restrict__ hw,
    const unsigned* __restrict__ mflag,
    float* __restrict__ ctx, float* __restrict__ ml)
{
    __shared__ __align__(16) u16 Ks[2][64 * 64];   // 16 KB  [key][d], swizzled
    __shared__ __align__(16) u16 Vs[2][64 * 64];   // 16 KB  [d][key], swizzled
    __shared__ __align__(16) u16 Pl[4][32 * 64];   // 16 KB  per-wave P (32 rows)

    const int usemask = (mflag[0] != 0);

    const int tid  = threadIdx.x;
    const int wave = tid >> 6;
    const int lane = tid & 63;
    const int l16  = lane & 15;
    const int quad = lane >> 4;
    const int x7   = l16 & 7;

    // XCD-aware remap: 512 blocks = 8 XCDs x 64; 4 whole (b,h) per XCD.
    const int lin = blockIdx.x + 16 * (blockIdx.y + 16 * blockIdx.z);
    const int xcd = lin & 7, jj = lin >> 3;
    const int qb  = jj & 15;                 // 16 q-blocks of 128 rows
    const int hb  = xcd * 4 + (jj >> 4);
    const int h   = hb & 15, b = hb >> 4;
    const int bh  = b * NH_ + h;

    const u16* Qh  = Q  + (size_t)bh * S_ * HD_;
    const u16* Kh  = K  + (size_t)bh * S_ * HD_;
    const u16* Vth = Vt + (size_t)bh * HD_ * S_;   // [d][s]
    const float* Mb = mask + (size_t)b * S_ * S_;

    const int q0 = qb * 128 + wave * 32;     // wave rows [q0, q0+32)

    bf16x8 qf0a = ld8(Qh + (size_t)(q0 + l16) * HD_ + quad * 8);
    bf16x8 qf1a = ld8(Qh + (size_t)(q0 + l16) * HD_ + 32 + quad * 8);
    bf16x8 qf0b = ld8(Qh + (size_t)(q0 + 16 + l16) * HD_ + quad * 8);
    bf16x8 qf1b = ld8(Qh + (size_t)(q0 + 16 + l16) * HD_ + 32 + quad * 8);

    // constant bf16 1.0 fragment for the denominator MFMA
    bf16x8 ones;
    #pragma unroll
    for (int e = 0; e < 8; e++) ones[e] = (short)0x3F80;

    f32x4 oacca[4] = {}, oaccb[4] = {};
    f32x4 lacca = {}, laccb = {};

    // gll staging geometry (R10): unit u covers tile rows u*8..u*8+7; lane's
    // global chunk pre-swizzled by row&7 so linear LDS write = swizzled layout.
    const int lrow = lane >> 3;                       // row&7
    const int lchk = ((lane & 7) ^ lrow) * 8;         // swizzled u16 chunk off
    const int u0   = wave * 2;                        // units u0, u0+1

    {   // prologue: stage tile 0
        gll16(Kh  + (size_t)(u0 * 8 +     lrow) * HD_ + lchk, &Ks[0][u0 * 512]);
        gll16(Kh  + (size_t)(u0 * 8 + 8 + lrow) * HD_ + lchk, &Ks[0][u0 * 512 + 512]);
        gll16(Vth + (size_t)(u0 * 8 +     lrow) * S_  + lchk, &Vs[0][u0 * 512]);
        gll16(Vth + (size_t)(u0 * 8 + 8 + lrow) * S_  + lchk, &Vs[0][u0 * 512 + 512]);
    }
    __syncthreads();

    for (int t = 0; t < 32; ++t) {
        const int cur = t & 1;
        const int kt  = t * 64;
        const u16* Kb = Ks[cur];
        const u16* Vb = Vs[cur];

        // issue next-tile gll16 EARLY (async; drained by the ending barrier)
        if (t < 31) {
            const u16* Kg = Kh + (size_t)(kt + 64) * HD_;
            gll16(Kg  + (size_t)(u0 * 8 +     lrow) * HD_ + lchk, &Ks[cur ^ 1][u0 * 512]);
            gll16(Kg  + (size_t)(u0 * 8 + 8 + lrow) * HD_ + lchk, &Ks[cur ^ 1][u0 * 512 + 512]);
            gll16(Vth + (size_t)(u0 * 8 +     lrow) * S_ + kt + 64 + lchk, &Vs[cur ^ 1][u0 * 512]);
            gll16(Vth + (size_t)(u0 * 8 + 8 + lrow) * S_ + kt + 64 + lchk, &Vs[cur ^ 1][u0 * 512 + 512]);
        }

        // --- S^T = K Q^T for both row-groups (K fragments shared) ---
        f32x4 sacca[4] = {}, saccb[4] = {};
        __builtin_amdgcn_s_setprio(1);
        #pragma unroll
        for (int nb = 0; nb < 4; nb++) {
            const int base = (nb * 16 + l16) * 64;
            bf16x8 k0 = ld8(&Kb[base + ((quad ^ x7) * 8)]);
            bf16x8 k1 = ld8(&Kb[base + (((quad + 4) ^ x7) * 8)]);
            sacca[nb] = __builtin_amdgcn_mfma_f32_16x16x32_bf16(k0, qf0a, sacca[nb], 0, 0, 0);
            sacca[nb] = __builtin_amdgcn_mfma_f32_16x16x32_bf16(k1, qf1a, sacca[nb], 0, 0, 0);
            saccb[nb] = __builtin_amdgcn_mfma_f32_16x16x32_bf16(k0, qf0b, saccb[nb], 0, 0, 0);
            saccb[nb] = __builtin_amdgcn_mfma_f32_16x16x32_bf16(k1, qf1b, saccb[nb], 0, 0, 0);
        }
        __builtin_amdgcn_s_setprio(0);

        // --- deferred softmax + P->bf16 pairs -> LDS (both halves) ---
        if (usemask) {
            const float* Mra = Mb + (size_t)(q0 + l16) * S_ + kt;
            const float* Mrb = Mb + (size_t)(q0 + 16 + l16) * S_ + kt;
            u16* prowa = &Pl[wave][l16 * 64];
            u16* prowb = &Pl[wave][(16 + l16) * 64];
            #pragma unroll
            for (int nb = 0; nb < 4; nb++) {
                const int ch  = 2 * nb + (quad >> 1);
                const int off = ((ch ^ x7) << 3) + ((quad & 1) << 2);
                const float4 ma = *(const float4*)(Mra + nb * 16 + quad * 4);
                uint2 wa;
                wa.x = cvtpk(ex2(fminf(fmaf(ma.x, LOG2E_, sacca[nb][0]), CLAMP2_)),
                             ex2(fminf(fmaf(ma.y, LOG2E_, sacca[nb][1]), CLAMP2_)));
                wa.y = cvtpk(ex2(fminf(fmaf(ma.z, LOG2E_, sacca[nb][2]), CLAMP2_)),
                             ex2(fminf(fmaf(ma.w, LOG2E_, sacca[nb][3]), CLAMP2_)));
                *(uint2*)&prowa[off] = wa;
                const float4 mbv = *(const float4*)(Mrb + nb * 16 + quad * 4);
                uint2 wb;
                wb.x = cvtpk(ex2(fminf(fmaf(mbv.x, LOG2E_, saccb[nb][0]), CLAMP2_)),
                             ex2(fminf(fmaf(mbv.y, LOG2E_, saccb[nb][1]), CLAMP2_)));
                wb.y = cvtpk(ex2(fminf(fmaf(mbv.z, LOG2E_, saccb[nb][2]), CLAMP2_)),
                             ex2(fminf(fmaf(mbv.w, LOG2E_, saccb[nb][3]), CLAMP2_)));
                *(uint2*)&prowb[off] = wb;
            }
        } else {
            u16* prowa = &Pl[wave][l16 * 64];
            u16* prowb = &Pl[wave][(16 + l16) * 64];
            #pragma unroll
            for (int nb = 0; nb < 4; nb++) {
                const int ch  = 2 * nb + (quad >> 1);
                const int off = ((ch ^ x7) << 3) + ((quad & 1) << 2);
                uint2 wa;
                wa.x = cvtpk(ex2(fminf(sacca[nb][0], CLAMP2_)),
                             ex2(fminf(sacca[nb][1], CLAMP2_)));
                wa.y = cvtpk(ex2(fminf(sacca[nb][2], CLAMP2_)),
                             ex2(fminf(sacca[nb][3], CLAMP2_)));
                *(uint2*)&prowa[off] = wa;
                uint2 wb;
                wb.x = cvtpk(ex2(fminf(saccb[nb][0], CLAMP2_)),
                             ex2(fminf(saccb[nb][1], CLAMP2_)));
                wb.y = cvtpk(ex2(fminf(saccb[nb][2], CLAMP2_)),
                             ex2(fminf(saccb[nb][3], CLAMP2_)));
                *(uint2*)&prowb[off] = wb;
            }
        }

        // --- O += P @ V ; l += P @ 1 (V fragments shared across halves) ---
        __builtin_amdgcn_s_setprio(1);
        #pragma unroll
        for (int kb = 0; kb < 2; kb++) {
            const int c = kb * 4 + quad;
            bf16x8 pfa = ld8(&Pl[wave][l16 * 64 + ((c ^ x7) * 8)]);
            bf16x8 pfb = ld8(&Pl[wave][(16 + l16) * 64 + ((c ^ x7) * 8)]);
            lacca = __builtin_amdgcn_mfma_f32_16x16x32_bf16(pfa, ones, lacca, 0, 0, 0);
            laccb = __builtin_amdgcn_mfma_f32_16x16x32_bf16(pfb, ones, laccb, 0, 0, 0);
            #pragma unroll
            for (int db = 0; db < 4; db++) {
                bf16x8 vf = ld8(&Vb[(db * 16 + l16) * 64 + ((c ^ x7) * 8)]);
                oacca[db] = __builtin_amdgcn_mfma_f32_16x16x32_bf16(pfa, vf, oacca[db], 0, 0, 0);
                oaccb[db] = __builtin_amdgcn_mfma_f32_16x16x32_bf16(pfb, vf, oaccb[db], 0, 0, 0);
            }
        }
        __builtin_amdgcn_s_setprio(0);

        __syncthreads();   // drains vmcnt (gll16) + lgkm before buffer swap
    }

    // --- epilogue: lacc[r] is l for q-row (grp*16 + quad*4+r) ---
    const float hwf = hw[h];
    float invla[4], invlb[4];
    #pragma unroll
    for (int r = 0; r < 4; r++) { invla[r] = hwf / lacca[r]; invlb[r] = hwf / laccb[r]; }

    #pragma unroll
    for (int db = 0; db < 4; db++)
        #pragma unroll
        for (int r = 0; r < 4; r++) {
            const int ra = q0 + quad * 4 + r;
            const int rb = q0 + 16 + quad * 4 + r;
            ctx[((size_t)(b * S_ + ra)) * HID_ + h * HD_ + db * 16 + l16] =
                oacca[db][r] * invla[r];
            ctx[((size_t)(b * S_ + rb)) * HID_ + h * HD_ + db * 16 + l16] =
                oaccb[db][r] * invlb[r];
        }

    // per-row l for the probs kernel (last 128 rows == qb 15 exactly)
    if (qb == 15 && l16 == 0) {
        #pragma unroll
        for (int r = 0; r < 4; r++) {
            ml[bh * 128 + (q0 - 1920) + quad * 4 + r]      = lacca[r];
            ml[bh * 128 + (q0 - 1920) + 16 + quad * 4 + r] = laccb[r];
        }
    }
}

// ---------------------------------------------------------------------------
// Stage 3: probs — recompute QK^T for the last 128 q rows (Q pre-scaled),
// swapped operands, float4 stores of normalized probs. Grid (16,16,2).
// ---------------------------------------------------------------------------
__global__ __launch_bounds__(256) void probs_qk(
    const u16* __restrict__ Q, const u16* __restrict__ K,
    const float* __restrict__ mask, const float* __restrict__ hw,
    const unsigned* __restrict__ mflag, const float* __restrict__ ml,
    float* __restrict__ probs_out)
{
    const int usemask = (mflag[0] != 0);

    const int tid  = threadIdx.x;
    const int wave = tid >> 6;
    const int lane = tid & 63;
    const int l16  = lane & 15;
    const int quad = lane >> 4;

    const int rt = blockIdx.x & 1;          // row-tile (64 rows)
    const int ks = blockIdx.x >> 1;         // key-eighth (256 keys)
    const int h  = blockIdx.y;
    const int b  = blockIdx.z;
    const int bh = b * NH_ + h;

    const u16* Qh = Q + (size_t)bh * S_ * HD_;
    const u16* Kh = K + (size_t)bh * S_ * HD_;
    const float* Mb = mask + (size_t)b * S_ * S_;

    const int q0   = 1920 + rt * 64 + wave * 16;
    const int qrow = q0 + l16;              // this lane's q row

    bf16x8 qf0 = ld8(Qh + (size_t)qrow * HD_ + quad * 8);
    bf16x8 qf1 = ld8(Qh + (size_t)qrow * HD_ + 32 + quad * 8);

    const float invl = hw[h] / ml[bh * 128 + (qrow - 1920)];
    float* Prow = probs_out + ((size_t)bh * 128 + (qrow - 1920)) * S_;
    const float* Mrow = Mb + (size_t)qrow * S_;

    for (int kt = ks * 256; kt < ks * 256 + 256; kt += 64) {
        f32x4 sacc[4] = {};
        #pragma unroll
        for (int nb = 0; nb < 4; nb++) {
            const u16* krow = Kh + (size_t)(kt + nb * 16 + l16) * HD_ + quad * 8;
            bf16x8 kA0 = ld8(krow);
            bf16x8 kA1 = ld8(krow + 32);
            sacc[nb] = __builtin_amdgcn_mfma_f32_16x16x32_bf16(kA0, qf0, sacc[nb], 0, 0, 0);
            sacc[nb] = __builtin_amdgcn_mfma_f32_16x16x32_bf16(kA1, qf1, sacc[nb], 0, 0, 0);
        }
        #pragma unroll
        for (int nb = 0; nb < 4; nb++) {
            const int kb0 = kt + nb * 16 + quad * 4;   // 4 contiguous keys
            float4 v;
            if (usemask) {
                const float4 mv = *(const float4*)&Mrow[kb0];
                v.x = ex2(fminf(fmaf(mv.x, LOG2E_, sacc[nb][0]), CLAMP2_)) * invl;
                v.y = ex2(fminf(fmaf(mv.y, LOG2E_, sacc[nb][1]), CLAMP2_)) * invl;
                v.z = ex2(fminf(fmaf(mv.z, LOG2E_, sacc[nb][2]), CLAMP2_)) * invl;
                v.w = ex2(fminf(fmaf(mv.w, LOG2E_, sacc[nb][3]), CLAMP2_)) * invl;
            } else {
                v.x = ex2(fminf(sacc[nb][0], CLAMP2_)) * invl;
                v.y = ex2(fminf(sacc[nb][1], CLAMP2_)) * invl;
                v.z = ex2(fminf(sacc[nb][2], CLAMP2_)) * invl;
                v.w = ex2(fminf(sacc[nb][3], CLAMP2_)) * invl;
            }
            *(float4*)&Prow[kb0] = v;
        }
    }
}

// ---------------------------------------------------------------------------
extern "C" void kernel_launch(void* const* d_in, const int* in_sizes, int n_in,
                              void* d_out, int out_size, void* d_ws, size_t ws_size,
                              hipStream_t stream)
{
    const void* X = 0; const void* mask = 0; const void* hw = 0;
    const void* Wm[3] = {0, 0, 0}; const void* bm[3] = {0, 0, 0};
    int wi = 0, bi = 0;
    for (int i = 0; i < n_in; i++) {
        switch (in_sizes[i]) {
            case 4194304: X = d_in[i]; break;
            case 8388608: mask = d_in[i]; break;
            case 1048576: if (wi < 3) Wm[wi++] = d_in[i]; break;
            case 1024:    if (bi < 3) bm[bi++] = d_in[i]; break;
            case 16:      hw = d_in[i]; break;
            default: break;
        }
    }
    if (!X || !mask || wi != 3 || bi != 3 || !hw) {
        X = d_in[0]; mask = d_in[1];
        Wm[0] = d_in[2]; bm[0] = d_in[3];
        Wm[1] = d_in[4]; bm[1] = d_in[5];
        Wm[2] = d_in[6]; bm[2] = d_in[7];
        hw = d_in[8];
    }

    u16* Q  = (u16*)d_ws;                    // 8 MB
    u16* Kw = Q + 4194304ull;                // 8 MB
    u16* Vw = Kw + 4194304ull;               // 8 MB (stored transposed per head)
    u16* Xb = Vw + 4194304ull;               // 8 MB
    u16* Wb = Xb + 4194304ull;               // 6 MB
    unsigned* flag = (unsigned*)(Wb + 3145728ull);   // 4 B @ 38 MB
    float* ml = (float*)(flag + 64);                 // 16 KB (l per probs row)

    float* ctx   = (float*)d_out;
    float* probs = ctx + (size_t)B_ * S_ * HID_;

    hipMemsetAsync(flag, 0, 4, stream);
    conv_scan<<<7680, 256, 0, stream>>>(
        (const float*)X, (const float*)Wm[0], (const float*)Wm[1], (const float*)Wm[2],
        (const unsigned*)mask, Xb, Wb, flag);

    qkv_mfma<<<dim3(32, 24), dim3(256), 0, stream>>>(
        Xb, Wb, (const float*)bm[0], (const float*)bm[1], (const float*)bm[2],
        Q, Kw, Vw);

    attn<<<dim3(16, 16, 2), dim3(256), 0, stream>>>(
        Q, Kw, Vw, (const float*)mask, (const float*)hw, flag, ctx, ml);

    probs_qk<<<dim3(16, 16, 2), dim3(256), 0, stream>>>(
        Q, Kw, (const float*)mask, (const float*)hw, flag, ml, probs);
}